// Round 2
// baseline (745.411 us; speedup 1.0000x reference)
//
#include <hip/hip_runtime.h>
#include <hip/hip_bf16.h>
#include <math.h>

#define NEG_SLOPE 0.2f

// ---------------------------------------------------------------------------
// CSR build: histogram -> single-block scan -> scatter
// NOTE: harness passes integer inputs as int32 (int64 in reference is
// converted) — edge_index is const int*, layout [src[0..E), dst[0..E)].
// ---------------------------------------------------------------------------
__global__ void hist_kernel(const int* __restrict__ ei, int E, int n,
                            int* __restrict__ counts) {
    int e = blockIdx.x * blockDim.x + threadIdx.x;
    int Etot = E + n;
    if (e >= Etot) return;
    int d = (e < E) ? ei[E + e] : (e - E);
    if ((unsigned)d >= (unsigned)n) return;   // defensive: never fault
    atomicAdd(&counts[d], 1);
}

// 1 block, 1024 threads. counts may alias cursor (read-then-overwrite per tile).
__global__ void scan_kernel(const int* __restrict__ counts,
                            int* __restrict__ row_ptr,
                            int* __restrict__ cursor, int n) {
    __shared__ int sm[1024];
    __shared__ int carry_s;
    int tid = threadIdx.x;
    if (tid == 0) carry_s = 0;
    __syncthreads();
    for (int base = 0; base < n; base += 1024) {
        int i = base + tid;
        int v = (i < n) ? counts[i] : 0;
        sm[tid] = v;
        __syncthreads();
        int x = v;
        for (int off = 1; off < 1024; off <<= 1) {
            int y = (tid >= off) ? sm[tid - off] : 0;
            __syncthreads();
            x += y;
            sm[tid] = x;
            __syncthreads();
        }
        int carry = carry_s;           // stable: last write was before a sync
        int excl = carry + (x - v);
        if (i < n) { row_ptr[i] = excl; cursor[i] = excl; }
        __syncthreads();
        if (tid == 1023) carry_s = carry + x;
        __syncthreads();
    }
    if (tid == 0) row_ptr[n] = carry_s;
}

__global__ void scatter_kernel(const int* __restrict__ ei, int E, int n,
                               int* __restrict__ cursor, int* __restrict__ col) {
    int e = blockIdx.x * blockDim.x + threadIdx.x;
    int Etot = E + n;
    if (e >= Etot) return;
    int s, d;
    if (e < E) {
        s = ei[e];
        d = ei[E + e];
    } else {
        s = d = e - E;
    }
    if ((unsigned)d >= (unsigned)n || (unsigned)s >= (unsigned)n) return;
    int pos = atomicAdd(&cursor[d], 1);
    col[pos] = s;
}

// ---------------------------------------------------------------------------
// Transform: h = x @ W  (no bias), e_src = (h*a_src).sum, e_dst = (h*a_dst).sum
// 32 lanes per node, lane f owns output feature f.
// ---------------------------------------------------------------------------
template <int IN_DIM>
__global__ void transform_kernel(const float* __restrict__ x,
                                 const float* __restrict__ W,
                                 const float* __restrict__ a_src,
                                 const float* __restrict__ a_dst,
                                 float* __restrict__ h,
                                 float* __restrict__ es,
                                 float* __restrict__ ed, int n) {
    __shared__ float Ws[IN_DIM * 32];
    for (int i = threadIdx.x; i < IN_DIM * 32; i += blockDim.x) Ws[i] = W[i];
    __syncthreads();
    int group = (blockIdx.x * blockDim.x + threadIdx.x) >> 5;
    int f = threadIdx.x & 31;
    if (group >= n) return;
    float x0 = x[group * IN_DIM + f];
    float x1 = (IN_DIM == 64) ? x[group * IN_DIM + 32 + f] : 0.f;
    float acc = 0.f;
#pragma unroll
    for (int k = 0; k < IN_DIM; ++k) {
        float xv = (k < 32) ? __shfl(x0, k, 32) : __shfl(x1, k - 32, 32);
        acc = fmaf(xv, Ws[k * 32 + f], acc);
    }
    h[group * 32 + f] = acc;
    float ps = acc * a_src[f];
    float pd = acc * a_dst[f];
#pragma unroll
    for (int off = 16; off; off >>= 1) {
        ps += __shfl_xor(ps, off, 32);
        pd += __shfl_xor(pd, off, 32);
    }
    if (f == 0) { es[group] = ps; ed[group] = pd; }
}

// ---------------------------------------------------------------------------
// Aggregation with online softmax. One 32-lane group per dst node; lane f owns
// feature f.
// ---------------------------------------------------------------------------
__device__ __forceinline__ void agg_core(const int* __restrict__ row_ptr,
                                         const int* __restrict__ col,
                                         const float* __restrict__ h,
                                         const float* __restrict__ es,
                                         float edv, int d, int f,
                                         float& out_acc, float& out_l) {
    int beg = row_ptr[d], end = row_ptr[d + 1];
    float m = -INFINITY, l = 0.f, acc = 0.f;
    for (int base = beg; base < end; base += 32) {
        int e = base + f;
        bool valid = e < end;
        int s = valid ? col[e] : 0;
        float a = -INFINITY;
        if (valid) {
            float t = es[s] + edv;
            a = (t > 0.f) ? t : NEG_SLOPE * t;
        }
        float cm = a;
#pragma unroll
        for (int off = 16; off; off >>= 1) cm = fmaxf(cm, __shfl_xor(cm, off, 32));
        float mn = fmaxf(m, cm);
        float scale = __expf(m - mn);   // exp(-inf)=0 on first chunk
        l *= scale;
        acc *= scale;
        m = mn;
        float ex = valid ? __expf(a - mn) : 0.f;
        l += ex;                        // per-lane partial denominator
        int cnt = min(32, end - base);
        for (int j = 0; j < cnt; ++j) {
            float w = __shfl(ex, j, 32);
            int sj = __shfl(s, j, 32);
            acc = fmaf(h[sj * 32 + f], w, acc);
        }
    }
#pragma unroll
    for (int off = 16; off; off >>= 1) l += __shfl_xor(l, off, 32);
    out_acc = acc;
    out_l = l;
}

__global__ void agg_kernel(const int* __restrict__ row_ptr,
                           const int* __restrict__ col,
                           const float* __restrict__ h,
                           const float* __restrict__ es,
                           const float* __restrict__ ed,
                           const float* __restrict__ bias,
                           float* __restrict__ out, int n) {
    int group = (blockIdx.x * blockDim.x + threadIdx.x) >> 5;
    int f = threadIdx.x & 31;
    if (group >= n) return;
    float acc, l;
    agg_core(row_ptr, col, h, es, ed[group], group, f, acc, l);
    float o = acc / l + bias[f];
    out[group * 32 + f] = fmaxf(o, 0.f);   // relu
}

// Final layer: aggregation + relu + (g @ lW + lb) [+ sigmoid]
__global__ void agg_linear_kernel(const int* __restrict__ row_ptr,
                                  const int* __restrict__ col,
                                  const float* __restrict__ h,
                                  const float* __restrict__ es,
                                  const float* __restrict__ ed,
                                  const float* __restrict__ bias,
                                  const float* __restrict__ lW,
                                  const float* __restrict__ lb,
                                  float* __restrict__ out, int n,
                                  int do_sigmoid) {
    __shared__ float lWs[32 * 32];
    for (int i = threadIdx.x; i < 1024; i += blockDim.x) lWs[i] = lW[i];
    __syncthreads();
    int group = (blockIdx.x * blockDim.x + threadIdx.x) >> 5;
    int f = threadIdx.x & 31;
    if (group >= n) return;
    float acc, l;
    agg_core(row_ptr, col, h, es, ed[group], group, f, acc, l);
    float g = fmaxf(acc / l + bias[f], 0.f);   // relu(gat2)
    float y = lb[f];
#pragma unroll
    for (int k = 0; k < 32; ++k) {
        float gk = __shfl(g, k, 32);
        y = fmaf(gk, lWs[k * 32 + f], y);
    }
    if (do_sigmoid) y = 1.f / (1.f + __expf(-y));
    out[group * 32 + f] = y;
}

// ---------------------------------------------------------------------------
// Launch
// ---------------------------------------------------------------------------
extern "C" void kernel_launch(void* const* d_in, const int* in_sizes, int n_in,
                              void* d_out, int out_size, void* d_ws, size_t ws_size,
                              hipStream_t stream) {
    const float* x = (const float*)d_in[0];
    const int* ei = (const int*)d_in[1];   // int32! harness converts int64
    const int N = in_sizes[0] / 64;
    const int E = in_sizes[1] / 2;
    const int Etot = E + N;

    // workspace carve-up (256B aligned); total ≈ 20.3 MB
    char* w = (char*)d_ws;
    size_t off = 0;
    auto alloc = [&](size_t bytes) {
        void* p = w + off;
        off = (off + bytes + 255) & ~(size_t)255;
        return p;
    };
    int* row_ptr = (int*)alloc((size_t)(N + 1) * 4);
    int* cursor  = (int*)alloc((size_t)N * 4);        // doubles as counts
    int* col     = (int*)alloc((size_t)Etot * 4);
    float* bufA  = (float*)alloc((size_t)N * 32 * 4);
    float* bufB  = (float*)alloc((size_t)N * 32 * 4);
    float* es    = (float*)alloc((size_t)N * 4);
    float* ed    = (float*)alloc((size_t)N * 4);
    (void)ws_size;

    float* out = (float*)d_out;

    const int edge_blocks = (Etot + 255) / 256;
    const int node_blocks = (N * 32 + 255) / 256;

    // ---- CSR build (graph shared by all 4 GAT layers) ----
    hipMemsetAsync(cursor, 0, (size_t)N * 4, stream);
    hist_kernel<<<edge_blocks, 256, 0, stream>>>(ei, E, N, cursor);
    scan_kernel<<<1, 1024, 0, stream>>>(cursor, row_ptr, cursor, N);
    scatter_kernel<<<edge_blocks, 256, 0, stream>>>(ei, E, N, cursor, col);

    // ---- two branches: c (sigmoid) at offset 0, r at offset N*32 ----
    for (int br = 0; br < 2; ++br) {
        int base = 2 + br * 10;
        const float* W1  = (const float*)d_in[base + 0];
        const float* as1 = (const float*)d_in[base + 1];
        const float* ad1 = (const float*)d_in[base + 2];
        const float* b1  = (const float*)d_in[base + 3];
        const float* W2  = (const float*)d_in[base + 4];
        const float* as2 = (const float*)d_in[base + 5];
        const float* ad2 = (const float*)d_in[base + 6];
        const float* b2  = (const float*)d_in[base + 7];
        const float* lW  = (const float*)d_in[base + 8];
        const float* lb  = (const float*)d_in[base + 9];
        float* bout = out + (size_t)br * N * 32;
        int do_sigmoid = (br == 0) ? 1 : 0;

        transform_kernel<64><<<node_blocks, 256, 0, stream>>>(
            x, W1, as1, ad1, bufA, es, ed, N);
        agg_kernel<<<node_blocks, 256, 0, stream>>>(
            row_ptr, col, bufA, es, ed, b1, bufB, N);
        transform_kernel<32><<<node_blocks, 256, 0, stream>>>(
            bufB, W2, as2, ad2, bufA, es, ed, N);
        agg_linear_kernel<<<node_blocks, 256, 0, stream>>>(
            row_ptr, col, bufA, es, ed, b2, lW, lb, bout, N, do_sigmoid);
    }
}

// Round 3
// 498.939 us; speedup vs baseline: 1.4940x; 1.4940x over previous
//
#include <hip/hip_runtime.h>
#include <hip/hip_bf16.h>
#include <math.h>

#define NEG_SLOPE 0.2f
#define NPART 8          // one dst-partition per XCD (blockIdx % 8 ~ XCD id)
#define CSR_BLOCKS 1024  // 128 blocks per partition

// ---------------------------------------------------------------------------
// CSR build, XCD-partitioned: each partition p owns dst range [lo,hi) so its
// col/cursor region stays resident in ONE XCD L2 -> full-line writebacks.
// edge_index layout (int32): [src[0..E), dst[0..E)], self-loops appended
// implicitly (edge id >= E -> s=d=id-E).
// ---------------------------------------------------------------------------
__global__ void hist_part_kernel(const int* __restrict__ ei, int E, int n,
                                 int* __restrict__ counts) {
    int pid = blockIdx.x & (NPART - 1);
    int bid = blockIdx.x >> 3;
    int nb  = gridDim.x >> 3;
    int lo = (int)((long long)pid * n / NPART);
    int hi = (int)((long long)(pid + 1) * n / NPART);
    int Etot = E + n;
    int stride = nb * blockDim.x;
    for (int i = bid * blockDim.x + threadIdx.x; i < Etot; i += stride) {
        int d = (i < E) ? ei[E + i] : (i - E);
        if (d >= lo && d < hi) atomicAdd(&counts[d], 1);
    }
}

__global__ void scatter_part_kernel(const int* __restrict__ ei, int E, int n,
                                    int* __restrict__ cursor,
                                    int* __restrict__ col) {
    int pid = blockIdx.x & (NPART - 1);
    int bid = blockIdx.x >> 3;
    int nb  = gridDim.x >> 3;
    int lo = (int)((long long)pid * n / NPART);
    int hi = (int)((long long)(pid + 1) * n / NPART);
    int Etot = E + n;
    int stride = nb * blockDim.x;
    for (int i = bid * blockDim.x + threadIdx.x; i < Etot; i += stride) {
        int d = (i < E) ? ei[E + i] : (i - E);
        if (d >= lo && d < hi) {
            int s = (i < E) ? ei[i] : d;
            if ((unsigned)s < (unsigned)n) {
                int pos = atomicAdd(&cursor[d], 1);
                col[pos] = s;
            }
        }
    }
}

// ---------------------------------------------------------------------------
// Hierarchical exclusive scan of counts[n] -> row_ptr[n+1], cursor[n]
// ---------------------------------------------------------------------------
__global__ void scan1_kernel(const int* __restrict__ counts,
                             int* __restrict__ bsum, int n) {
    __shared__ int sm[256];
    int i = blockIdx.x * 256 + threadIdx.x;
    sm[threadIdx.x] = (i < n) ? counts[i] : 0;
    __syncthreads();
    for (int off = 128; off; off >>= 1) {
        if (threadIdx.x < off) sm[threadIdx.x] += sm[threadIdx.x + off];
        __syncthreads();
    }
    if (threadIdx.x == 0) bsum[blockIdx.x] = sm[0];
}

// single block; nb <= 256 (n=50k -> nb=196)
__global__ void scan2_kernel(int* __restrict__ bsum, int nb) {
    __shared__ int sm[256];
    int t = threadIdx.x;
    int v = (t < nb) ? bsum[t] : 0;
    sm[t] = v;
    __syncthreads();
    int x = v;
    for (int off = 1; off < 256; off <<= 1) {
        int y = (t >= off) ? sm[t - off] : 0;
        __syncthreads();
        x += y;
        sm[t] = x;
        __syncthreads();
    }
    if (t < nb) bsum[t] = x - v;          // exclusive block offsets
    if (t == nb - 1) bsum[nb] = x;        // grand total
}

__global__ void scan3_kernel(const int* __restrict__ counts,
                             const int* __restrict__ bsum,
                             int* __restrict__ row_ptr,
                             int* __restrict__ cursor, int n, int nb) {
    __shared__ int sm[256];
    int t = threadIdx.x;
    int i = blockIdx.x * 256 + t;
    int v = (i < n) ? counts[i] : 0;
    sm[t] = v;
    __syncthreads();
    int x = v;
    for (int off = 1; off < 256; off <<= 1) {
        int y = (t >= off) ? sm[t - off] : 0;
        __syncthreads();
        x += y;
        sm[t] = x;
        __syncthreads();
    }
    int excl = bsum[blockIdx.x] + x - v;
    if (i < n) { row_ptr[i] = excl; cursor[i] = excl; }
    if (i == 0) row_ptr[n] = bsum[nb];
}

// ---------------------------------------------------------------------------
// Branch-fused transform layer 1: h = x@W for BOTH branches, interleaved as
// float2 {c,r} per feature. Also es/ed for both branches (float2).
// ---------------------------------------------------------------------------
__global__ void t1_fused_kernel(const float* __restrict__ x,
                                const float* __restrict__ Wc,
                                const float* __restrict__ Wr,
                                const float* __restrict__ asc,
                                const float* __restrict__ adc,
                                const float* __restrict__ asr,
                                const float* __restrict__ adr,
                                float2* __restrict__ h,
                                float2* __restrict__ es2,
                                float2* __restrict__ ed2, int n) {
    __shared__ float Wsc[64 * 32];
    __shared__ float Wsr[64 * 32];
    for (int i = threadIdx.x; i < 64 * 32; i += blockDim.x) {
        Wsc[i] = Wc[i];
        Wsr[i] = Wr[i];
    }
    __syncthreads();
    int group = (blockIdx.x * blockDim.x + threadIdx.x) >> 5;
    int f = threadIdx.x & 31;
    if (group >= n) return;
    float x0 = x[group * 64 + f];
    float x1 = x[group * 64 + 32 + f];
    float ac = 0.f, ar = 0.f;
#pragma unroll
    for (int k = 0; k < 64; ++k) {
        float xv = (k < 32) ? __shfl(x0, k, 32) : __shfl(x1, k - 32, 32);
        ac = fmaf(xv, Wsc[k * 32 + f], ac);
        ar = fmaf(xv, Wsr[k * 32 + f], ar);
    }
    h[group * 32 + f] = make_float2(ac, ar);
    float psc = ac * asc[f], pdc = ac * adc[f];
    float psr = ar * asr[f], pdr = ar * adr[f];
#pragma unroll
    for (int off = 16; off; off >>= 1) {
        psc += __shfl_xor(psc, off, 32);
        pdc += __shfl_xor(pdc, off, 32);
        psr += __shfl_xor(psr, off, 32);
        pdr += __shfl_xor(pdr, off, 32);
    }
    if (f == 0) {
        es2[group] = make_float2(psc, psr);
        ed2[group] = make_float2(pdc, pdr);
    }
}

// Branch-fused transform layer 2 (32-dim input, float2-interleaved)
__global__ void t2_fused_kernel(const float2* __restrict__ g,
                                const float* __restrict__ Wc,
                                const float* __restrict__ Wr,
                                const float* __restrict__ asc,
                                const float* __restrict__ adc,
                                const float* __restrict__ asr,
                                const float* __restrict__ adr,
                                float2* __restrict__ h,
                                float2* __restrict__ es2,
                                float2* __restrict__ ed2, int n) {
    __shared__ float Wsc[32 * 32];
    __shared__ float Wsr[32 * 32];
    for (int i = threadIdx.x; i < 32 * 32; i += blockDim.x) {
        Wsc[i] = Wc[i];
        Wsr[i] = Wr[i];
    }
    __syncthreads();
    int group = (blockIdx.x * blockDim.x + threadIdx.x) >> 5;
    int f = threadIdx.x & 31;
    if (group >= n) return;
    float2 v = g[group * 32 + f];
    float ac = 0.f, ar = 0.f;
#pragma unroll
    for (int k = 0; k < 32; ++k) {
        float xc = __shfl(v.x, k, 32);
        float xr = __shfl(v.y, k, 32);
        ac = fmaf(xc, Wsc[k * 32 + f], ac);
        ar = fmaf(xr, Wsr[k * 32 + f], ar);
    }
    h[group * 32 + f] = make_float2(ac, ar);
    float psc = ac * asc[f], pdc = ac * adc[f];
    float psr = ar * asr[f], pdr = ar * adr[f];
#pragma unroll
    for (int off = 16; off; off >>= 1) {
        psc += __shfl_xor(psc, off, 32);
        pdc += __shfl_xor(pdc, off, 32);
        psr += __shfl_xor(psr, off, 32);
        pdr += __shfl_xor(pdr, off, 32);
    }
    if (f == 0) {
        es2[group] = make_float2(psc, psr);
        ed2[group] = make_float2(pdc, pdr);
    }
}

// ---------------------------------------------------------------------------
// Branch-fused online-softmax aggregation core. One 32-lane group per dst;
// lane f owns feature f of both branches (float2 {c,r}).
// ---------------------------------------------------------------------------
__device__ __forceinline__ void agg_core2(const int* __restrict__ row_ptr,
                                          const int* __restrict__ col,
                                          const float2* __restrict__ h,
                                          const float2* __restrict__ es2,
                                          float2 edv, int d, int f,
                                          float& oac, float& oar,
                                          float& olc, float& olr) {
    int beg = row_ptr[d], end = row_ptr[d + 1];
    float mc = -INFINITY, mr = -INFINITY;
    float lc = 0.f, lr = 0.f, ac = 0.f, ar = 0.f;
    for (int base = beg; base < end; base += 32) {
        int e = base + f;
        bool valid = e < end;
        int s = valid ? col[e] : 0;
        float avc = -INFINITY, avr = -INFINITY;
        if (valid) {
            float2 ess = es2[s];
            float tc = ess.x + edv.x;
            float tr = ess.y + edv.y;
            avc = (tc > 0.f) ? tc : NEG_SLOPE * tc;
            avr = (tr > 0.f) ? tr : NEG_SLOPE * tr;
        }
        float cmc = avc, cmr = avr;
#pragma unroll
        for (int off = 16; off; off >>= 1) {
            cmc = fmaxf(cmc, __shfl_xor(cmc, off, 32));
            cmr = fmaxf(cmr, __shfl_xor(cmr, off, 32));
        }
        float mnc = fmaxf(mc, cmc), mnr = fmaxf(mr, cmr);
        float scc = __expf(mc - mnc), scr = __expf(mr - mnr);
        lc *= scc; ac *= scc; mc = mnc;
        lr *= scr; ar *= scr; mr = mnr;
        float exc = valid ? __expf(avc - mnc) : 0.f;
        float exr = valid ? __expf(avr - mnr) : 0.f;
        lc += exc; lr += exr;
        int cnt = min(32, end - base);
        for (int j = 0; j < cnt; ++j) {
            float wc = __shfl(exc, j, 32);
            float wr = __shfl(exr, j, 32);
            int sj = __shfl(s, j, 32);
            float2 hv = h[sj * 32 + f];
            ac = fmaf(hv.x, wc, ac);
            ar = fmaf(hv.y, wr, ar);
        }
    }
#pragma unroll
    for (int off = 16; off; off >>= 1) {
        lc += __shfl_xor(lc, off, 32);
        lr += __shfl_xor(lr, off, 32);
    }
    oac = ac; oar = ar; olc = lc; olr = lr;
}

// Layer-1 agg: writes relu(agg + bias) for both branches, interleaved.
__global__ void agg1_fused_kernel(const int* __restrict__ row_ptr,
                                  const int* __restrict__ col,
                                  const float2* __restrict__ h,
                                  const float2* __restrict__ es2,
                                  const float2* __restrict__ ed2,
                                  const float* __restrict__ bc,
                                  const float* __restrict__ br,
                                  float2* __restrict__ out, int n) {
    int group = (blockIdx.x * blockDim.x + threadIdx.x) >> 5;
    int f = threadIdx.x & 31;
    if (group >= n) return;
    float ac, ar, lc, lr;
    agg_core2(row_ptr, col, h, es2, ed2[group], group, f, ac, ar, lc, lr);
    float gc = fmaxf(ac / lc + bc[f], 0.f);
    float gr = fmaxf(ar / lr + br[f], 0.f);
    out[group * 32 + f] = make_float2(gc, gr);
}

// Layer-2 agg + relu + linear (+ sigmoid on branch c). Writes final output:
// out[0..n*32) = sigmoid branch, out[n*32..2*n*32) = regressor branch.
__global__ void agg2_lin_fused_kernel(const int* __restrict__ row_ptr,
                                      const int* __restrict__ col,
                                      const float2* __restrict__ h,
                                      const float2* __restrict__ es2,
                                      const float2* __restrict__ ed2,
                                      const float* __restrict__ bc,
                                      const float* __restrict__ br,
                                      const float* __restrict__ lWc,
                                      const float* __restrict__ lWr,
                                      const float* __restrict__ lbc,
                                      const float* __restrict__ lbr,
                                      float* __restrict__ out, int n) {
    __shared__ float Wsc[32 * 32];
    __shared__ float Wsr[32 * 32];
    for (int i = threadIdx.x; i < 32 * 32; i += blockDim.x) {
        Wsc[i] = lWc[i];
        Wsr[i] = lWr[i];
    }
    __syncthreads();
    int group = (blockIdx.x * blockDim.x + threadIdx.x) >> 5;
    int f = threadIdx.x & 31;
    if (group >= n) return;
    float ac, ar, lc, lr;
    agg_core2(row_ptr, col, h, es2, ed2[group], group, f, ac, ar, lc, lr);
    float gc = fmaxf(ac / lc + bc[f], 0.f);
    float gr = fmaxf(ar / lr + br[f], 0.f);
    float yc = lbc[f], yr = lbr[f];
#pragma unroll
    for (int k = 0; k < 32; ++k) {
        float gkc = __shfl(gc, k, 32);
        float gkr = __shfl(gr, k, 32);
        yc = fmaf(gkc, Wsc[k * 32 + f], yc);
        yr = fmaf(gkr, Wsr[k * 32 + f], yr);
    }
    yc = 1.f / (1.f + __expf(-yc));   // sigmoid (classifier branch)
    out[group * 32 + f] = yc;
    out[(size_t)n * 32 + group * 32 + f] = yr;
}

// ---------------------------------------------------------------------------
// Launch
// ---------------------------------------------------------------------------
extern "C" void kernel_launch(void* const* d_in, const int* in_sizes, int n_in,
                              void* d_out, int out_size, void* d_ws, size_t ws_size,
                              hipStream_t stream) {
    const float* x = (const float*)d_in[0];
    const int* ei = (const int*)d_in[1];   // int32; [src(E), dst(E)]
    const int N = in_sizes[0] / 64;
    const int E = in_sizes[1] / 2;
    const int Etot = E + N;

    // branch c = inputs 2..11, branch r = inputs 12..21
    const float* cW1  = (const float*)d_in[2];
    const float* cas1 = (const float*)d_in[3];
    const float* cad1 = (const float*)d_in[4];
    const float* cb1  = (const float*)d_in[5];
    const float* cW2  = (const float*)d_in[6];
    const float* cas2 = (const float*)d_in[7];
    const float* cad2 = (const float*)d_in[8];
    const float* cb2  = (const float*)d_in[9];
    const float* clW  = (const float*)d_in[10];
    const float* clb  = (const float*)d_in[11];
    const float* rW1  = (const float*)d_in[12];
    const float* ras1 = (const float*)d_in[13];
    const float* rad1 = (const float*)d_in[14];
    const float* rb1  = (const float*)d_in[15];
    const float* rW2  = (const float*)d_in[16];
    const float* ras2 = (const float*)d_in[17];
    const float* rad2 = (const float*)d_in[18];
    const float* rb2  = (const float*)d_in[19];
    const float* rlW  = (const float*)d_in[20];
    const float* rlb  = (const float*)d_in[21];

    // workspace carve-up (256B aligned); ~33.5 MB
    char* w = (char*)d_ws;
    size_t off = 0;
    auto alloc = [&](size_t bytes) {
        void* p = w + off;
        off = (off + bytes + 255) & ~(size_t)255;
        return p;
    };
    int*    row_ptr = (int*)alloc((size_t)(N + 1) * 4);
    int*    counts  = (int*)alloc((size_t)N * 4);
    int*    cursor  = (int*)alloc((size_t)N * 4);
    int*    bsum    = (int*)alloc(257 * 4);
    int*    col     = (int*)alloc((size_t)Etot * 4);
    float2* bufA    = (float2*)alloc((size_t)N * 32 * 8);  // h1, reused as h2
    float2* bufB    = (float2*)alloc((size_t)N * 32 * 8);  // g1
    float2* es2     = (float2*)alloc((size_t)N * 8);
    float2* ed2     = (float2*)alloc((size_t)N * 8);
    (void)ws_size;

    float* out = (float*)d_out;

    const int node_blocks = (N * 32 + 255) / 256;
    const int scan_blocks = (N + 255) / 256;   // 196 (<=256 required by scan2)

    // ---- CSR build (graph shared by all 4 GAT layers) ----
    hipMemsetAsync(counts, 0, (size_t)N * 4, stream);
    hist_part_kernel<<<CSR_BLOCKS, 256, 0, stream>>>(ei, E, N, counts);
    scan1_kernel<<<scan_blocks, 256, 0, stream>>>(counts, bsum, N);
    scan2_kernel<<<1, 256, 0, stream>>>(bsum, scan_blocks);
    scan3_kernel<<<scan_blocks, 256, 0, stream>>>(counts, bsum, row_ptr, cursor, N, scan_blocks);
    scatter_part_kernel<<<CSR_BLOCKS, 256, 0, stream>>>(ei, E, N, cursor, col);

    // ---- branch-fused pipeline ----
    t1_fused_kernel<<<node_blocks, 256, 0, stream>>>(
        x, cW1, rW1, cas1, cad1, ras1, rad1, bufA, es2, ed2, N);
    agg1_fused_kernel<<<node_blocks, 256, 0, stream>>>(
        row_ptr, col, bufA, es2, ed2, cb1, rb1, bufB, N);
    t2_fused_kernel<<<node_blocks, 256, 0, stream>>>(
        bufB, cW2, rW2, cas2, cad2, ras2, rad2, bufA, es2, ed2, N);
    agg2_lin_fused_kernel<<<node_blocks, 256, 0, stream>>>(
        row_ptr, col, bufA, es2, ed2, cb2, rb2, clW, rlW, clb, rlb, out, N);
}